// Round 4
// baseline (604.919 us; speedup 1.0000x reference)
//
#include <hip/hip_runtime.h>

typedef unsigned short u16;
typedef __bf16 bf16x8 __attribute__((ext_vector_type(8)));
typedef float f32x4 __attribute__((ext_vector_type(4)));
typedef u16 u16x8 __attribute__((ext_vector_type(8)));

#define M_DIM 8192
#define N_DIM 4096
#define K_DIM 4096
#define BK 64

__device__ __forceinline__ u16 f2b(float f) {
  unsigned int x = __float_as_uint(f);
  unsigned int r = (x + 0x7fffu + ((x >> 16) & 1u)) >> 16;
  return (u16)r;
}

#define GLOAD_LDS16(gp, lp)                                        \
  __builtin_amdgcn_global_load_lds(                                \
      (const __attribute__((address_space(1))) void*)(gp),         \
      (__attribute__((address_space(3))) void*)(lp), 16, 0, 0)

// ---------------------------------------------------------------------------
// Kernel 0: convert x fp32 -> bf16. 8 elements / thread.
// ---------------------------------------------------------------------------
__global__ __launch_bounds__(256) void cvt_x(const float* __restrict__ X,
                                             u16* __restrict__ Xb) {
  const size_t t = (size_t)blockIdx.x * 256 + threadIdx.x;
  const f32x4* src = (const f32x4*)X + t * 2;
  f32x4 a = src[0];
  f32x4 b = src[1];
  u16x8 o;
  o[0] = f2b(a[0]); o[1] = f2b(a[1]); o[2] = f2b(a[2]); o[3] = f2b(a[3]);
  o[4] = f2b(b[0]); o[5] = f2b(b[1]); o[6] = f2b(b[2]); o[7] = f2b(b[3]);
  *((u16x8*)Xb + t) = o;
}

// ---------------------------------------------------------------------------
// Kernel 1: Weff[o][d] = W[o][d] + sum_u Bu[o][u]*Au[u][d] + sum_r Bs[o][r]*As[r][d]
//   As[r][d] = d<2048 ? A0[r][d] : A0[(r-1)%56][d-2048]
//   Bs[o][r] = o<2048 ? B0[o][r] : B0[o-2048][(r-1)%56]
// Block: 16 o-rows x 1024 d; grid (4, 256); bf16 output.
// ---------------------------------------------------------------------------
__global__ __launch_bounds__(256) void build_weff(
    const float* __restrict__ W, const float* __restrict__ Au,
    const float* __restrict__ Bu, const float* __restrict__ A0,
    const float* __restrict__ B0, u16* __restrict__ Weff) {
  __shared__ float coef[64 * 16];  // coef[r][oi]
  const int t = threadIdx.x;
  const int o0 = blockIdx.y * 16;

#pragma unroll
  for (int j = 0; j < 4; j++) {
    const int idx = t + j * 256;     // 0..1023
    const int r = idx >> 4;          // 0..63
    const int oi = idx & 15;
    const int o = o0 + oi;
    float v;
    if (r < 8) {
      v = Bu[o * 8 + r];
    } else {
      const int rs = r - 8;
      if (o < 2048) {
        v = B0[o * 56 + rs];
      } else {
        const int rr = rs ? (rs - 1) : 55;
        v = B0[(o - 2048) * 56 + rr];
      }
    }
    coef[r * 16 + oi] = v;
  }
  __syncthreads();

  const int d0 = blockIdx.x * 1024 + t * 4;
  const int hi = (d0 >= 2048);
  const int dd = hi ? (d0 - 2048) : d0;

  f32x4 acc[16] = {};

#pragma unroll
  for (int r = 0; r < 8; r++) {
    f32x4 a = *(const f32x4*)(Au + (size_t)r * 4096 + d0);
    const float* cr = &coef[r * 16];
#pragma unroll
    for (int oi = 0; oi < 16; oi++) {
      const float c = cr[oi];
      acc[oi][0] += c * a[0]; acc[oi][1] += c * a[1];
      acc[oi][2] += c * a[2]; acc[oi][3] += c * a[3];
    }
  }
#pragma unroll 4
  for (int rs = 0; rs < 56; rs++) {
    const int rr = hi ? (rs ? (rs - 1) : 55) : rs;
    f32x4 a = *(const f32x4*)(A0 + (size_t)rr * 2048 + dd);
    const float* cr = &coef[(rs + 8) * 16];
#pragma unroll
    for (int oi = 0; oi < 16; oi++) {
      const float c = cr[oi];
      acc[oi][0] += c * a[0]; acc[oi][1] += c * a[1];
      acc[oi][2] += c * a[2]; acc[oi][3] += c * a[3];
    }
  }

#pragma unroll
  for (int oi = 0; oi < 16; oi++) {
    f32x4 w = *(const f32x4*)(W + (size_t)(o0 + oi) * 4096 + d0);
    ushort4 ov;
    ov.x = f2b(acc[oi][0] + w[0]);
    ov.y = f2b(acc[oi][1] + w[1]);
    ov.z = f2b(acc[oi][2] + w[2]);
    ov.w = f2b(acc[oi][3] + w[3]);
    *(ushort4*)(Weff + (size_t)(o0 + oi) * 4096 + d0) = ov;
  }
}

// ---------------------------------------------------------------------------
// Kernel 2: C[m][n] = sum_k Xb[m][k]*Weff[n][k] + bias[n]  (bf16 MFMA, NT)
// m97 linear staging: 128x128 tile, 4 waves 2x2, 64x64/wave, BK=64,
// global_load_lds(16B). OUTPUT IS FP32 (reference output dtype).
// ---------------------------------------------------------------------------
__global__ __launch_bounds__(256, 2) void gemm_bt_bias(
    const u16* __restrict__ X, const u16* __restrict__ Wf,
    const float* __restrict__ bias, float* __restrict__ C) {
  __shared__ __align__(16) u16 As[128 * BK];
  __shared__ __align__(16) u16 Bs[128 * BK];

  const int tid = threadIdx.x;
  const int wave = tid >> 6;
  const int lane = tid & 63;
  const int wm = wave >> 1;   // 0..1
  const int wn = wave & 1;    // 0..1
  const int quad = lane >> 4; // 0..3
  const int l16 = lane & 15;  // 0..15

  const int n0 = blockIdx.x * 128;
  const int m0 = blockIdx.y * 128;

  f32x4 acc[4][4] = {};

  // Staging: wave covers 32 rows of A and B (4 issues of 8 rows x 64 k).
  // Deposit = wave-uniform LDS base + lane*16 (m104/m108): lane i -> row i>>3,
  // colblock i&7. Source = identical linear mapping (m97-verified).
  const int srow = lane >> 3;   // 0..7
  const int scb = lane & 7;     // 0..7

  const u16* xg = X + (size_t)(m0 + wave * 32 + srow) * K_DIM + scb * 8;
  const u16* wg = Wf + (size_t)(n0 + wave * 32 + srow) * K_DIM + scb * 8;
  u16* asb = &As[wave * 32 * BK];
  u16* bsb = &Bs[wave * 32 * BK];

  for (int kt = 0; kt < K_DIM; kt += BK) {
#pragma unroll
    for (int q = 0; q < 4; q++) {
      GLOAD_LDS16(xg + (size_t)q * 8 * K_DIM + kt, asb + q * 8 * BK);
      GLOAD_LDS16(wg + (size_t)q * 8 * K_DIM + kt, bsb + q * 8 * BK);
    }
    __syncthreads();

#pragma unroll
    for (int kk = 0; kk < 2; kk++) {
      bf16x8 af[4], bfv[4];
      const int cb = (kk << 2) + quad;  // linear colblock
#pragma unroll
      for (int i = 0; i < 4; i++) {
        af[i] = *(const bf16x8*)(&As[(wm * 64 + i * 16 + l16) * BK + cb * 8]);
        bfv[i] = *(const bf16x8*)(&Bs[(wn * 64 + i * 16 + l16) * BK + cb * 8]);
      }
#pragma unroll
      for (int i = 0; i < 4; i++)
#pragma unroll
        for (int j = 0; j < 4; j++)
          acc[i][j] = __builtin_amdgcn_mfma_f32_16x16x32_bf16(
              af[i], bfv[j], acc[i][j], 0, 0, 0);
    }
    __syncthreads();
  }

  // Epilogue: C/D layout col=lane&15, row=quad*4+reg (m89/m91-verified).
  // FP32 stores — reference output dtype is float32.
#pragma unroll
  for (int j = 0; j < 4; j++) {
    const int col = n0 + wn * 64 + j * 16 + l16;
    const float bv = bias[col];
#pragma unroll
    for (int i = 0; i < 4; i++) {
      const int row = m0 + wm * 64 + i * 16 + quad * 4;
#pragma unroll
      for (int r = 0; r < 4; r++) {
        C[(size_t)(row + r) * N_DIM + col] = acc[i][j][r] + bv;
      }
    }
  }
}

extern "C" void kernel_launch(void* const* d_in, const int* in_sizes, int n_in,
                              void* d_out, int out_size, void* d_ws, size_t ws_size,
                              hipStream_t stream) {
  const float* x  = (const float*)d_in[0];  // [4,2048,4096] fp32
  const float* W  = (const float*)d_in[1];  // [4096,4096] fp32
  const float* b  = (const float*)d_in[2];  // [4096] fp32
  const float* Au = (const float*)d_in[3];  // [8,4096] fp32
  const float* Bu = (const float*)d_in[4];  // [4096,8] fp32
  const float* A0 = (const float*)d_in[5];  // [56,2048] fp32
  const float* B0 = (const float*)d_in[6];  // [2048,56] fp32
  float* out = (float*)d_out;               // [4,2048,4096] fp32

  u16* Xb   = (u16*)d_ws;                                      // 64 MB
  u16* Weff = (u16*)((char*)d_ws + (size_t)64 * 1024 * 1024);  // 32 MB

  cvt_x<<<16384, 256, 0, stream>>>(x, Xb);
  build_weff<<<dim3(4, 256), 256, 0, stream>>>(W, Au, Bu, A0, B0, Weff);
  gemm_bt_bias<<<dim3(N_DIM / 128, M_DIM / 128), 256, 0, stream>>>(Xb, Weff, b, out);
}